// Round 12
// baseline (1578.785 us; speedup 1.0000x reference)
//
#include <hip/hip_runtime.h>
#include <hip/hip_bf16.h>
#include <hip/hip_fp16.h>

#define NN 80000
#define NE 1280000
#define NL 4
#define NG 256

__device__ __forceinline__ float wave_sum(float v) {
    for (int off = 32; off; off >>= 1) v += __shfl_xor(v, off, 64);
    return v;
}

// ---------------- CSR build ----------------
__global__ void k_count(const int* __restrict__ idx, int* __restrict__ cnt) {
    int e = blockIdx.x * 256 + threadIdx.x;
    if (e < NE) atomicAdd(&cnt[idx[e]], 1);
}

__global__ void k_scan1(const int* __restrict__ in, int* __restrict__ out,
                        int* __restrict__ bsum, int n) {
    __shared__ int ws[4];
    int i = blockIdx.x * 256 + threadIdx.x;
    int v = (i < n) ? in[i] : 0;
    int lane = threadIdx.x & 63, w = threadIdx.x >> 6;
    for (int off = 1; off < 64; off <<= 1) {
        int t = __shfl_up(v, off, 64);
        if (lane >= off) v += t;
    }
    if (lane == 63) ws[w] = v;
    __syncthreads();
    if (threadIdx.x == 0) {
        int acc = 0;
        for (int k = 0; k < 4; k++) { int t = ws[k]; ws[k] = acc; acc += t; }
    }
    __syncthreads();
    v += ws[w];
    if (i < n) out[i] = v;
    if (threadIdx.x == 255) bsum[blockIdx.x] = v;
}

__global__ void k_scan2(int* __restrict__ bsum, int nb) {
    __shared__ int ws[4];
    __shared__ int carry;
    if (threadIdx.x == 0) carry = 0;
    __syncthreads();
    for (int base = 0; base < nb; base += 256) {
        int i = base + threadIdx.x;
        int v = (i < nb) ? bsum[i] : 0;
        int lane = threadIdx.x & 63, w = threadIdx.x >> 6;
        for (int off = 1; off < 64; off <<= 1) {
            int t = __shfl_up(v, off, 64);
            if (lane >= off) v += t;
        }
        if (lane == 63) ws[w] = v;
        __syncthreads();
        if (threadIdx.x == 0) {
            int acc = carry;
            for (int k = 0; k < 4; k++) { int t = ws[k]; ws[k] = acc; acc += t; }
            carry = acc;
        }
        __syncthreads();
        v += ws[w];
        if (i < nb) bsum[i] = v;
        __syncthreads();
    }
}

__global__ void k_scan3(int* __restrict__ rowptr, const int* __restrict__ bsum, int n) {
    int i = blockIdx.x * 256 + threadIdx.x;
    if (i < n) {
        int off = (blockIdx.x > 0) ? bsum[blockIdx.x - 1] : 0;
        rowptr[1 + i] += off;
    }
    if (i == 0 && blockIdx.x == 0) rowptr[0] = 0;
}

// Build BOTH CSRs in one pass.
// csr32[posD]  = (src<<10)|combo    (dst-CSR, for fallback path)
// srccsr[posS] = (posD<<10)|combo   (src-CSR, for 2-phase path; posD < 2^21)
__global__ void k_fill(const int* __restrict__ src, const int* __restrict__ dst,
                       const int* __restrict__ eattr,
                       const int* __restrict__ rowptrD, int* __restrict__ wofsD,
                       const int* __restrict__ rowptrS, int* __restrict__ wofsS,
                       int* __restrict__ csr32, int* __restrict__ srccsr) {
    int e = blockIdx.x * 256 + threadIdx.x;
    if (e >= NE) return;
    int s = src[e], d = dst[e];
    int a0 = eattr[e * 3], a1 = eattr[e * 3 + 1], a2 = eattr[e * 3 + 2];
    int combo = a0 + a1 * 10 + a2 * 100;
    int posD = rowptrD[d] + atomicAdd(&wofsD[d], 1);
    csr32[posD] = (s << 10) | combo;
    int posS = rowptrS[s] + atomicAdd(&wofsS[s], 1);
    srccsr[posS] = (posD << 10) | combo;
}

// ---------------- encoders / weight packing ----------------
__global__ void k_comb(const float* __restrict__ bond_emb, __half* __restrict__ comb) {
    int wid = (blockIdx.x * 256 + threadIdx.x) >> 6;
    int lane = threadIdx.x & 63;
    if (wid >= 1000) return;
    int a0 = wid % 10, a1 = (wid / 10) % 10, a2 = wid / 100;
    comb[wid * 64 + lane] = __float2half(bond_emb[a0 * 64 + lane] +
                                         bond_emb[(10 + a1) * 64 + lane] +
                                         bond_emb[(20 + a2) * 64 + lane]);
}

__global__ void k_atom(const int* __restrict__ x, const float* __restrict__ atom_emb,
                       __half* __restrict__ xn) {
    int wid = (blockIdx.x * 256 + threadIdx.x) >> 6;
    int lane = threadIdx.x & 63;
    if (wid >= NN) return;
    float acc = 0.f;
#pragma unroll
    for (int f = 0; f < 9; f++) {
        int idx = x[wid * 9 + f] + f * 100;
        acc += atom_emb[idx * 64 + lane];
    }
    xn[wid * 64 + lane] = __float2half(acc);
}

// W1p[l][k][lane] = {W1[l][k][lane], W1[l][k][64+lane]}
// W2p[l][j][lane] = {W2[l][j][lane], W2[l][64+j][lane]}
__global__ void k_packw(const float* __restrict__ W1, const float* __restrict__ W2,
                        float2* __restrict__ W1p, float2* __restrict__ W2p) {
    int i = blockIdx.x * 256 + threadIdx.x;
    if (i >= NL * 64 * 64) return;
    int lane = i & 63, k = (i >> 6) & 63, l = i >> 12;
    W1p[i] = make_float2(W1[(l * 64 + k) * 128 + lane],
                         W1[(l * 64 + k) * 128 + 64 + lane]);
    W2p[i] = make_float2(W2[(l * 128 + k) * 64 + lane],
                         W2[(l * 128 + 64 + k) * 64 + lane]);
}

// ---------------- PHASE 1: materialize per-edge messages (src-major, scatter-write) ----
__global__ __launch_bounds__(256) void k_msg(
    const __half* __restrict__ hin, const int* __restrict__ rowptrS,
    const int* __restrict__ srccsr, const __half* __restrict__ comb,
    __half* __restrict__ emsg) {
    int s = blockIdx.x * 4 + (threadIdx.x >> 6);   // NN == 20000*4
    int lane = threadIdx.x & 63;
    float h = __half2float(hin[(long)s * 64 + lane]);
    int rs = rowptrS[s], re = rowptrS[s + 1];
#pragma unroll 4
    for (int p = rs; p < re; ++p) {
        int v = srccsr[p];
        float c = __half2float(comb[(v & 1023) * 64 + lane]);
        float m = fmaxf(h + c, 0.f) + 1e-7f;
        emsg[(long)(v >> 10) * 64 + lane] = __float2half(m);
    }
}

// ---------------- PHASE 2: streaming softmax-agg + LDS-weight MLP + prenorm ----------
__global__ __launch_bounds__(1024) void k_conv2(
    const __half* __restrict__ hin, const int* __restrict__ rowptr,
    const __half* __restrict__ emsg, const float* __restrict__ t, int l,
    const float2* __restrict__ W1p, const float* __restrict__ b1,
    const float* __restrict__ g1, const float* __restrict__ bb1,
    const float2* __restrict__ W2p, const float* __restrict__ b2,
    float* __restrict__ cur, int residual,
    __half* __restrict__ hh, const float* __restrict__ ng, const float* __restrict__ nb) {
    __shared__ float2 sW[8192];
    {
        const float2* W1l = W1p + l * 4096;
        const float2* W2l = W2p + l * 4096;
        for (int i = threadIdx.x; i < 4096; i += 1024) {
            sW[i] = W1l[i];
            sW[4096 + i] = W2l[i];
        }
    }
    __syncthreads();

    int wid = blockIdx.x * 16 + (threadIdx.x >> 6);   // NN == 5000*16
    int lane = threadIdx.x & 63;
    float tl = t[l];
    long oi = (long)wid * 64 + lane;
    float hroot = __half2float(hin[oi]);
    int rs = rowptr[wid], re = rowptr[wid + 1];
    int n = re - rs;
    const __half* ep = emsg + (long)rs * 64 + lane;

    // ---- streaming branch-free softmax aggregation (contiguous rows) ----
    float den0 = 0.f, num0 = 0.f, den1 = 0.f, num1 = 0.f;
    float den2 = 0.f, num2 = 0.f, den3 = 0.f, num3 = 0.f;
    int q = 0, n8 = n & ~7;
    for (; q < n8; q += 8) {
        float m0 = __half2float(ep[(long)(q + 0) * 64]);
        float m1 = __half2float(ep[(long)(q + 1) * 64]);
        float m2 = __half2float(ep[(long)(q + 2) * 64]);
        float m3 = __half2float(ep[(long)(q + 3) * 64]);
        float m4 = __half2float(ep[(long)(q + 4) * 64]);
        float m5 = __half2float(ep[(long)(q + 5) * 64]);
        float m6 = __half2float(ep[(long)(q + 6) * 64]);
        float m7 = __half2float(ep[(long)(q + 7) * 64]);
        float e0 = __expf(m0 * tl), e1 = __expf(m1 * tl);
        float e2 = __expf(m2 * tl), e3 = __expf(m3 * tl);
        float e4 = __expf(m4 * tl), e5 = __expf(m5 * tl);
        float e6 = __expf(m6 * tl), e7 = __expf(m7 * tl);
        den0 += e0; num0 = fmaf(e0, m0, num0);
        den1 += e1; num1 = fmaf(e1, m1, num1);
        den2 += e2; num2 = fmaf(e2, m2, num2);
        den3 += e3; num3 = fmaf(e3, m3, num3);
        den0 += e4; num0 = fmaf(e4, m4, num0);
        den1 += e5; num1 = fmaf(e5, m5, num1);
        den2 += e6; num2 = fmaf(e6, m6, num2);
        den3 += e7; num3 = fmaf(e7, m7, num3);
    }
    for (; q < n; ++q) {
        float m = __half2float(ep[(long)q * 64]);
        float e = __expf(m * tl);
        den0 += e; num0 = fmaf(e, m, num0);
    }
    float den = (den0 + den1) + (den2 + den3);
    float num = (num0 + num1) + (num2 + num3);
    float o = num / (den + 1e-16f) + hroot;
    float curold = residual ? cur[oi] : 0.f;

    // ---- MLP 64 -> 128 -> LN -> ReLU -> 64 (weights in LDS) ----
    float a0 = b1[l * 128 + lane];
    float a1 = b1[l * 128 + 64 + lane];
#pragma unroll 8
    for (int k = 0; k < 64; ++k) {
        float ok = __shfl(o, k, 64);
        float2 w = sW[k * 64 + lane];
        a0 = fmaf(ok, w.x, a0);
        a1 = fmaf(ok, w.y, a1);
    }
    float mu = wave_sum(a0 + a1) * (1.f / 128.f);
    float d0 = a0 - mu, d1 = a1 - mu;
    float var = wave_sum(d0 * d0 + d1 * d1) * (1.f / 128.f);
    float r = rsqrtf(var + 1e-5f);
    float m0 = fmaxf(d0 * r * g1[l * 128 + lane] + bb1[l * 128 + lane], 0.f);
    float m1 = fmaxf(d1 * r * g1[l * 128 + 64 + lane] + bb1[l * 128 + 64 + lane], 0.f);
    float acc = b2[l * 64 + lane];
#pragma unroll 8
    for (int j = 0; j < 64; ++j) {
        float v0 = __shfl(m0, j, 64);
        float v1 = __shfl(m1, j, 64);
        float2 w = sW[4096 + j * 64 + lane];
        acc = fmaf(v0, w.x, acc);
        acc = fmaf(v1, w.y, acc);
    }
    float curv = curold + acc;
    cur[oi] = curv;

    if (hh) {
        float mu2 = wave_sum(curv) * (1.f / 64.f);
        float dd = curv - mu2;
        float var2 = wave_sum(dd * dd) * (1.f / 64.f);
        hh[oi] = __float2half(fmaxf(dd * rsqrtf(var2 + 1e-5f) * ng[lane] + nb[lane], 0.f));
    }
}

// ---------------- FALLBACK conv (R10-proven: gather + LDS weights) ----------------
__global__ __launch_bounds__(1024) void k_conv(
    const __half* __restrict__ hin, const int* __restrict__ rowptr,
    const int* __restrict__ csr32, const __half* __restrict__ comb,
    const float* __restrict__ t, int l,
    const float2* __restrict__ W1p, const float* __restrict__ b1,
    const float* __restrict__ g1, const float* __restrict__ bb1,
    const float2* __restrict__ W2p, const float* __restrict__ b2,
    float* __restrict__ cur, int residual,
    __half* __restrict__ hh, const float* __restrict__ ng, const float* __restrict__ nb) {
    __shared__ float2 sW[8192];
    {
        const float2* W1l = W1p + l * 4096;
        const float2* W2l = W2p + l * 4096;
        for (int i = threadIdx.x; i < 4096; i += 1024) {
            sW[i] = W1l[i];
            sW[4096 + i] = W2l[i];
        }
    }
    __syncthreads();
    int wid = blockIdx.x * 16 + (threadIdx.x >> 6);
    int lane = threadIdx.x & 63;
    float tl = t[l];
    long oi = (long)wid * 64 + lane;
    float hroot = __half2float(hin[oi]);
    int rs = rowptr[wid], re = rowptr[wid + 1];
    float den = 0.f, num = 0.f;
#pragma unroll 4
    for (int p = rs; p < re; ++p) {
        int v = csr32[p];
        float h = __half2float(hin[(long)(v >> 10) * 64 + lane]);
        float c = __half2float(comb[(v & 1023) * 64 + lane]);
        float m = fmaxf(h + c, 0.f) + 1e-7f;
        float e = __expf(m * tl);
        den += e;
        num = fmaf(e, m, num);
    }
    float o = num / (den + 1e-16f) + hroot;
    float curold = residual ? cur[oi] : 0.f;
    float a0 = b1[l * 128 + lane];
    float a1 = b1[l * 128 + 64 + lane];
#pragma unroll 8
    for (int k = 0; k < 64; ++k) {
        float ok = __shfl(o, k, 64);
        float2 w = sW[k * 64 + lane];
        a0 = fmaf(ok, w.x, a0);
        a1 = fmaf(ok, w.y, a1);
    }
    float mu = wave_sum(a0 + a1) * (1.f / 128.f);
    float d0 = a0 - mu, d1 = a1 - mu;
    float var = wave_sum(d0 * d0 + d1 * d1) * (1.f / 128.f);
    float r = rsqrtf(var + 1e-5f);
    float m0 = fmaxf(d0 * r * g1[l * 128 + lane] + bb1[l * 128 + lane], 0.f);
    float m1 = fmaxf(d1 * r * g1[l * 128 + 64 + lane] + bb1[l * 128 + 64 + lane], 0.f);
    float acc = b2[l * 64 + lane];
#pragma unroll 8
    for (int j = 0; j < 64; ++j) {
        float v0 = __shfl(m0, j, 64);
        float v1 = __shfl(m1, j, 64);
        float2 w = sW[4096 + j * 64 + lane];
        acc = fmaf(v0, w.x, acc);
        acc = fmaf(v1, w.y, acc);
    }
    float curv = curold + acc;
    cur[oi] = curv;
    if (hh) {
        float mu2 = wave_sum(curv) * (1.f / 64.f);
        float dd = curv - mu2;
        float var2 = wave_sum(dd * dd) * (1.f / 64.f);
        hh[oi] = __float2half(fmaxf(dd * rsqrtf(var2 + 1e-5f) * ng[lane] + nb[lane], 0.f));
    }
}

// ---------------- pooling (atomic-free, batch sorted) ----------------
__global__ void k_bounds(const int* __restrict__ batch, int* __restrict__ gstart) {
    int i = blockIdx.x * 256 + threadIdx.x;
    if (i >= NN) return;
    int b = batch[i];
    if (i == 0) {
        for (int g = 0; g <= b; ++g) gstart[g] = 0;
    } else {
        int pb = batch[i - 1];
        for (int g = pb + 1; g <= b; ++g) gstart[g] = i;
    }
    if (i == NN - 1) {
        for (int g = b + 1; g <= NG; ++g) gstart[g] = NN;
    }
}

__global__ __launch_bounds__(1024) void k_pool2(
    const float* __restrict__ cur, const int* __restrict__ gstart,
    const float* __restrict__ g, const float* __restrict__ b,
    float* __restrict__ out) {
    int gi = blockIdx.x;
    int lane = threadIdx.x & 63, w = threadIdx.x >> 6;
    int s = gstart[gi], e = gstart[gi + 1];
    float gg = g[lane], bb = b[lane];
    float acc = 0.f;
    for (int n = s + w; n < e; n += 16) {
        float v = cur[(long)n * 64 + lane];
        float mu = wave_sum(v) * (1.f / 64.f);
        float d = v - mu;
        float var = wave_sum(d * d) * (1.f / 64.f);
        acc += fmaxf(d * rsqrtf(var + 1e-5f) * gg + bb, 0.f);
    }
    __shared__ float sh[16][64];
    sh[w][lane] = acc;
    __syncthreads();
    if (w == 0) {
        float tot = 0.f;
#pragma unroll
        for (int k = 0; k < 16; ++k) tot += sh[k][lane];
        out[gi * 64 + lane] = tot / fmaxf((float)(e - s), 1.f);
    }
}

extern "C" void kernel_launch(void* const* d_in, const int* in_sizes, int n_in,
                              void* d_out, int out_size, void* d_ws, size_t ws_size,
                              hipStream_t stream) {
    (void)in_sizes; (void)n_in; (void)out_size;
    const int* x         = (const int*)d_in[0];
    const int* edge_attr = (const int*)d_in[1];
    const int* src       = (const int*)d_in[2];
    const int* dst       = src + NE;
    const int* batch     = (const int*)d_in[3];
    const float* atom_emb = (const float*)d_in[4];
    const float* bond_emb = (const float*)d_in[5];
    const float* t        = (const float*)d_in[6];
    const float* W1       = (const float*)d_in[7];
    const float* b1       = (const float*)d_in[8];
    const float* g1       = (const float*)d_in[9];
    const float* bb1      = (const float*)d_in[10];
    const float* W2       = (const float*)d_in[11];
    const float* b2       = (const float*)d_in[12];
    const float* norm_g   = (const float*)d_in[13];
    const float* norm_b   = (const float*)d_in[14];
    float* out = (float*)d_out;

    size_t off = 0;
    auto alloc = [&](size_t bytes) {
        void* p = (char*)d_ws + off;
        off += (bytes + 255) & ~(size_t)255;
        return p;
    };
    int*    countD  = (int*)alloc((size_t)NN * 4);
    int*    wofsD   = (int*)alloc((size_t)NN * 4);
    int*    countS  = (int*)alloc((size_t)NN * 4);
    int*    wofsS   = (int*)alloc((size_t)NN * 4);
    int*    rowptrD = (int*)alloc((size_t)(NN + 1) * 4);
    int*    rowptrS = (int*)alloc((size_t)(NN + 1) * 4);
    int*    bsum    = (int*)alloc(4096);
    int*    csr32   = (int*)alloc((size_t)NE * 4);
    int*    srccsr  = (int*)alloc((size_t)NE * 4);
    __half* comb    = (__half*)alloc(1000 * 64 * 2);
    __half* xnH     = (__half*)alloc((size_t)NN * 64 * 2);
    __half* hhH     = (__half*)alloc((size_t)NN * 64 * 2);
    float*  cur     = (float*)alloc((size_t)NN * 64 * 4);
    int*    gstart  = (int*)alloc((size_t)(NG + 1) * 4);
    float2* W1p     = (float2*)alloc((size_t)NL * 64 * 64 * 8);
    float2* W2p     = (float2*)alloc((size_t)NL * 64 * 64 * 8);
    __half* emsg    = (__half*)alloc((size_t)NE * 64 * 2);
    bool twophase = ws_size >= off;

    hipMemsetAsync(countD, 0, (size_t)NN * 4, stream);
    hipMemsetAsync(wofsD, 0, (size_t)NN * 4, stream);
    hipMemsetAsync(countS, 0, (size_t)NN * 4, stream);
    hipMemsetAsync(wofsS, 0, (size_t)NN * 4, stream);

    const int EB = (NE + 255) / 256;
    const int SB = (NN + 255) / 256;
    const int WB = (NN * 64 + 255) / 256;

    k_count<<<EB, 256, 0, stream>>>(dst, countD);
    k_scan1<<<SB, 256, 0, stream>>>(countD, rowptrD + 1, bsum, NN);
    k_scan2<<<1, 256, 0, stream>>>(bsum, SB);
    k_scan3<<<SB, 256, 0, stream>>>(rowptrD, bsum, NN);
    k_count<<<EB, 256, 0, stream>>>(src, countS);
    k_scan1<<<SB, 256, 0, stream>>>(countS, rowptrS + 1, bsum, NN);
    k_scan2<<<1, 256, 0, stream>>>(bsum, SB);
    k_scan3<<<SB, 256, 0, stream>>>(rowptrS, bsum, NN);
    k_fill<<<EB, 256, 0, stream>>>(src, dst, edge_attr, rowptrD, wofsD,
                                   rowptrS, wofsS, csr32, srccsr);
    k_comb<<<(1000 * 64 + 255) / 256, 256, 0, stream>>>(bond_emb, comb);
    k_atom<<<WB, 256, 0, stream>>>(x, atom_emb, xnH);
    k_bounds<<<SB, 256, 0, stream>>>(batch, gstart);
    k_packw<<<(NL * 64 * 64 + 255) / 256, 256, 0, stream>>>(W1, W2, W1p, W2p);

    // Ping-pong: L0 reads xnH -> writes hhH ; L1 hhH->xnH ; L2 xnH->hhH ; L3 hhH->none.
    const int CB = NN / 16;   // 5000 blocks, 16 waves each
    const int MB = NN / 4;    // 20000 blocks for k_msg
    __half* bufs[2] = {hhH, xnH};
    for (int l = 0; l < NL; ++l) {
        __half* hin    = (l == 0) ? xnH : bufs[(l + 1) & 1];
        __half* hh_out = (l < NL - 1) ? bufs[l & 1] : nullptr;
        const float* ng  = norm_g + (l + 1 < NL ? (l + 1) * 64 : 0);
        const float* nbp = norm_b + (l + 1 < NL ? (l + 1) * 64 : 0);
        if (twophase) {
            k_msg<<<MB, 256, 0, stream>>>(hin, rowptrS, srccsr, comb, emsg);
            k_conv2<<<CB, 1024, 0, stream>>>(hin, rowptrD, emsg, t, l,
                                             W1p, b1, g1, bb1, W2p, b2,
                                             cur, l > 0, hh_out, ng, nbp);
        } else {
            k_conv<<<CB, 1024, 0, stream>>>(hin, rowptrD, csr32, comb, t, l,
                                            W1p, b1, g1, bb1, W2p, b2,
                                            cur, l > 0, hh_out, ng, nbp);
        }
    }
    k_pool2<<<NG, 1024, 0, stream>>>(cur, gstart, norm_g, norm_b, out);
}

// Round 13
// 541.350 us; speedup vs baseline: 2.9164x; 2.9164x over previous
//
#include <hip/hip_runtime.h>
#include <hip/hip_bf16.h>
#include <hip/hip_fp16.h>

#define NN 80000
#define NE 1280000
#define NL 4
#define NG 256

typedef __attribute__((ext_vector_type(8))) _Float16 half8;
typedef __attribute__((ext_vector_type(4))) float f32x4;

__device__ __forceinline__ float wave_sum(float v) {
    for (int off = 32; off; off >>= 1) v += __shfl_xor(v, off, 64);
    return v;
}

// ---------------- CSR build ----------------
__global__ void k_count(const int* __restrict__ idx, int* __restrict__ cnt) {
    int e = blockIdx.x * 256 + threadIdx.x;
    if (e < NE) atomicAdd(&cnt[idx[e]], 1);
}

__global__ void k_scan1(const int* __restrict__ in, int* __restrict__ out,
                        int* __restrict__ bsum, int n) {
    __shared__ int ws[4];
    int i = blockIdx.x * 256 + threadIdx.x;
    int v = (i < n) ? in[i] : 0;
    int lane = threadIdx.x & 63, w = threadIdx.x >> 6;
    for (int off = 1; off < 64; off <<= 1) {
        int t = __shfl_up(v, off, 64);
        if (lane >= off) v += t;
    }
    if (lane == 63) ws[w] = v;
    __syncthreads();
    if (threadIdx.x == 0) {
        int acc = 0;
        for (int k = 0; k < 4; k++) { int t = ws[k]; ws[k] = acc; acc += t; }
    }
    __syncthreads();
    v += ws[w];
    if (i < n) out[i] = v;
    if (threadIdx.x == 255) bsum[blockIdx.x] = v;
}

__global__ void k_scan2(int* __restrict__ bsum, int nb) {
    __shared__ int ws[4];
    __shared__ int carry;
    if (threadIdx.x == 0) carry = 0;
    __syncthreads();
    for (int base = 0; base < nb; base += 256) {
        int i = base + threadIdx.x;
        int v = (i < nb) ? bsum[i] : 0;
        int lane = threadIdx.x & 63, w = threadIdx.x >> 6;
        for (int off = 1; off < 64; off <<= 1) {
            int t = __shfl_up(v, off, 64);
            if (lane >= off) v += t;
        }
        if (lane == 63) ws[w] = v;
        __syncthreads();
        if (threadIdx.x == 0) {
            int acc = carry;
            for (int k = 0; k < 4; k++) { int t = ws[k]; ws[k] = acc; acc += t; }
            carry = acc;
        }
        __syncthreads();
        v += ws[w];
        if (i < nb) bsum[i] = v;
        __syncthreads();
    }
}

__global__ void k_scan3(int* __restrict__ rowptr, const int* __restrict__ bsum, int n) {
    int i = blockIdx.x * 256 + threadIdx.x;
    if (i < n) {
        int off = (blockIdx.x > 0) ? bsum[blockIdx.x - 1] : 0;
        rowptr[1 + i] += off;
    }
    if (i == 0 && blockIdx.x == 0) rowptr[0] = 0;
}

__global__ void k_fill(const int* __restrict__ src, const int* __restrict__ dst,
                       const int* __restrict__ eattr, const int* __restrict__ rowptr,
                       int* __restrict__ wofs, int* __restrict__ csr32) {
    int e = blockIdx.x * 256 + threadIdx.x;
    if (e >= NE) return;
    int d = dst[e];
    int pos = rowptr[d] + atomicAdd(&wofs[d], 1);
    int a0 = eattr[e * 3], a1 = eattr[e * 3 + 1], a2 = eattr[e * 3 + 2];
    csr32[pos] = (src[e] << 10) | (a0 + a1 * 10 + a2 * 100);
}

// ---------------- encoders / weight packing ----------------
__global__ void k_comb(const float* __restrict__ bond_emb, __half* __restrict__ comb) {
    int wid = (blockIdx.x * 256 + threadIdx.x) >> 6;
    int lane = threadIdx.x & 63;
    if (wid >= 1000) return;
    int a0 = wid % 10, a1 = (wid / 10) % 10, a2 = wid / 100;
    comb[wid * 64 + lane] = __float2half(bond_emb[a0 * 64 + lane] +
                                         bond_emb[(10 + a1) * 64 + lane] +
                                         bond_emb[(20 + a2) * 64 + lane]);
}

__global__ void k_atom(const int* __restrict__ x, const float* __restrict__ atom_emb,
                       __half* __restrict__ xn) {
    int wid = (blockIdx.x * 256 + threadIdx.x) >> 6;
    int lane = threadIdx.x & 63;
    if (wid >= NN) return;
    float acc = 0.f;
#pragma unroll
    for (int f = 0; f < 9; f++) {
        int idx = x[wid * 9 + f] + f * 100;
        acc += atom_emb[idx * 64 + lane];
    }
    xn[wid * 64 + lane] = __float2half(acc);
}

// w1t[l][n(128)][k(64)] = W1[l][k][n] ;  w2t[l][n(64)][k(128)] = W2[l][k][n]  (fp16, B^T layout)
__global__ void k_packw(const float* __restrict__ W1, const float* __restrict__ W2,
                        __half* __restrict__ w1t, __half* __restrict__ w2t) {
    int i = blockIdx.x * 256 + threadIdx.x;
    if (i >= NL * 8192) return;
    int l = i >> 13, r = i & 8191;
    int n1 = r >> 6, k1 = r & 63;
    w1t[i] = __float2half(W1[(l * 64 + k1) * 128 + n1]);
    int n2 = r >> 7, k2 = r & 127;
    w2t[i] = __float2half(W2[(l * 128 + k2) * 64 + n2]);
}

// ---------------- aggregation only: per-node wave, gather + online softmax ----------------
__global__ __launch_bounds__(256) void k_agg(
    const __half* __restrict__ hin, const int* __restrict__ rowptr,
    const int* __restrict__ csr32, const __half* __restrict__ comb,
    const float* __restrict__ t, int l, __half* __restrict__ o) {
    int wid = blockIdx.x * 4 + (threadIdx.x >> 6);   // NN == 20000*4
    int lane = threadIdx.x & 63;
    float tl = t[l];
    long oi = (long)wid * 64 + lane;
    float hroot = __half2float(hin[oi]);
    int rs = rowptr[wid], re = rowptr[wid + 1];
    float den = 0.f, num = 0.f;
#pragma unroll 4
    for (int p = rs; p < re; ++p) {
        int v = csr32[p];
        float h = __half2float(hin[(long)(v >> 10) * 64 + lane]);
        float c = __half2float(comb[(v & 1023) * 64 + lane]);
        float m = fmaxf(h + c, 0.f) + 1e-7f;
        float e = __expf(m * tl);
        den += e;
        num = fmaf(e, m, num);
    }
    o[oi] = __float2half(num / (den + 1e-16f) + hroot);
}

// ---------------- MFMA MLP: 16 nodes/wave, 4 waves/block ----------------
// z1 = o@W1+b1 -> LN128 -> relu -> LDS transpose -> z2 = mid@W2+b2 -> cur(+res) -> prenorm hh
__global__ __launch_bounds__(256) void k_mlp(
    const __half* __restrict__ o, int l,
    const __half* __restrict__ w1t, const __half* __restrict__ w2t,
    const float* __restrict__ b1, const float* __restrict__ g1,
    const float* __restrict__ bb1, const float* __restrict__ b2,
    float* __restrict__ cur, int residual,
    __half* __restrict__ hh, const float* __restrict__ ng, const float* __restrict__ nbv) {
    __shared__ __half midL[4][16][136];   // per-wave region, padded rows (136 halves)
    int w = threadIdx.x >> 6, lane = threadIdx.x & 63;
    int node0 = blockIdx.x * 64 + w * 16;           // NN == 1250*64
    int lm = lane & 15, lh = lane >> 4;             // lh in 0..3

    // ---- stage 1: A = o[16x64], B = w1t (B^T layout), 8 n-blocks x K=64 ----
    const __half* ob = o + (long)(node0 + lm) * 64 + lh * 8;
    half8 a0 = *(const half8*)(ob);
    half8 a1 = *(const half8*)(ob + 32);
    const __half* w1b = w1t + l * 8192 + lm * 64 + lh * 8;
    f32x4 acc[8];
#pragma unroll
    for (int nb = 0; nb < 8; ++nb) {
        f32x4 c = {0.f, 0.f, 0.f, 0.f};
        half8 b0 = *(const half8*)(w1b + nb * 1024);
        half8 bx = *(const half8*)(w1b + nb * 1024 + 32);
        c = __builtin_amdgcn_mfma_f32_16x16x32_f16(a0, b0, c, 0, 0, 0);
        c = __builtin_amdgcn_mfma_f32_16x16x32_f16(a1, bx, c, 0, 0, 0);
        acc[nb] = c;
    }

    // ---- +b1, LN over 128 cols (row = node = lh*4+reg, spread over 16-lane group) ----
    float bv[8], gv[8], bbv[8];
#pragma unroll
    for (int nb = 0; nb < 8; ++nb) {
        int n = l * 128 + nb * 16 + lm;
        bv[nb] = b1[n]; gv[nb] = g1[n]; bbv[nb] = bb1[n];
    }
    float ps[4] = {0.f, 0.f, 0.f, 0.f};
#pragma unroll
    for (int nb = 0; nb < 8; ++nb)
#pragma unroll
        for (int r = 0; r < 4; ++r) { acc[nb][r] += bv[nb]; ps[r] += acc[nb][r]; }
#pragma unroll
    for (int r = 0; r < 4; ++r) {
        for (int off = 1; off < 16; off <<= 1) ps[r] += __shfl_xor(ps[r], off, 64);
        ps[r] *= (1.f / 128.f);
    }
    float pv[4] = {0.f, 0.f, 0.f, 0.f};
#pragma unroll
    for (int nb = 0; nb < 8; ++nb)
#pragma unroll
        for (int r = 0; r < 4; ++r) { float d = acc[nb][r] - ps[r]; pv[r] = fmaf(d, d, pv[r]); }
#pragma unroll
    for (int r = 0; r < 4; ++r) {
        for (int off = 1; off < 16; off <<= 1) pv[r] += __shfl_xor(pv[r], off, 64);
        pv[r] = rsqrtf(pv[r] * (1.f / 128.f) + 1e-5f);
    }
#pragma unroll
    for (int nb = 0; nb < 8; ++nb)
#pragma unroll
        for (int r = 0; r < 4; ++r) {
            float m = fmaxf((acc[nb][r] - ps[r]) * pv[r] * gv[nb] + bbv[nb], 0.f);
            midL[w][lh * 4 + r][nb * 16 + lm] = __float2half(m);
        }

    // ---- stage 2: A' = mid[16x128] from LDS, B = w2t, 4 n-blocks x K=128 ----
    const __half* mrow = &midL[w][lm][lh * 8];
    const __half* w2b = w2t + l * 8192 + lm * 128 + lh * 8;
    f32x4 acc2[4];
#pragma unroll
    for (int nb = 0; nb < 4; ++nb) acc2[nb] = (f32x4){0.f, 0.f, 0.f, 0.f};
#pragma unroll
    for (int kb = 0; kb < 4; ++kb) {
        half8 a = *(const half8*)(mrow + kb * 32);
#pragma unroll
        for (int nb = 0; nb < 4; ++nb) {
            half8 b = *(const half8*)(w2b + nb * 2048 + kb * 32);
            acc2[nb] = __builtin_amdgcn_mfma_f32_16x16x32_f16(a, b, acc2[nb], 0, 0, 0);
        }
    }

    // ---- epilogue: +b2, residual, write cur, fused prenorm hh ----
    float b2v[4], cps[4] = {0.f, 0.f, 0.f, 0.f};
    float cv[4][4];
#pragma unroll
    for (int nb = 0; nb < 4; ++nb) b2v[nb] = b2[l * 64 + nb * 16 + lm];
#pragma unroll
    for (int nb = 0; nb < 4; ++nb)
#pragma unroll
        for (int r = 0; r < 4; ++r) {
            long ci = (long)(node0 + lh * 4 + r) * 64 + nb * 16 + lm;
            float z = acc2[nb][r] + b2v[nb] + (residual ? cur[ci] : 0.f);
            cur[ci] = z;
            cv[nb][r] = z;
            cps[r] += z;
        }
    if (hh) {
        float gn[4], bn[4], mu[4], rv[4];
        float pvv[4] = {0.f, 0.f, 0.f, 0.f};
#pragma unroll
        for (int nb = 0; nb < 4; ++nb) { gn[nb] = ng[nb * 16 + lm]; bn[nb] = nbv[nb * 16 + lm]; }
#pragma unroll
        for (int r = 0; r < 4; ++r) {
            float s = cps[r];
            for (int off = 1; off < 16; off <<= 1) s += __shfl_xor(s, off, 64);
            mu[r] = s * (1.f / 64.f);
        }
#pragma unroll
        for (int nb = 0; nb < 4; ++nb)
#pragma unroll
            for (int r = 0; r < 4; ++r) { float d = cv[nb][r] - mu[r]; pvv[r] = fmaf(d, d, pvv[r]); }
#pragma unroll
        for (int r = 0; r < 4; ++r) {
            float s = pvv[r];
            for (int off = 1; off < 16; off <<= 1) s += __shfl_xor(s, off, 64);
            rv[r] = rsqrtf(s * (1.f / 64.f) + 1e-5f);
        }
#pragma unroll
        for (int nb = 0; nb < 4; ++nb)
#pragma unroll
            for (int r = 0; r < 4; ++r) {
                long ci = (long)(node0 + lh * 4 + r) * 64 + nb * 16 + lm;
                hh[ci] = __float2half(fmaxf((cv[nb][r] - mu[r]) * rv[r] * gn[nb] + bn[nb], 0.f));
            }
    }
}

// ---------------- pooling (atomic-free, batch sorted) ----------------
__global__ void k_bounds(const int* __restrict__ batch, int* __restrict__ gstart) {
    int i = blockIdx.x * 256 + threadIdx.x;
    if (i >= NN) return;
    int b = batch[i];
    if (i == 0) {
        for (int g = 0; g <= b; ++g) gstart[g] = 0;
    } else {
        int pb = batch[i - 1];
        for (int g = pb + 1; g <= b; ++g) gstart[g] = i;
    }
    if (i == NN - 1) {
        for (int g = b + 1; g <= NG; ++g) gstart[g] = NN;
    }
}

__global__ __launch_bounds__(1024) void k_pool2(
    const float* __restrict__ cur, const int* __restrict__ gstart,
    const float* __restrict__ g, const float* __restrict__ b,
    float* __restrict__ out) {
    int gi = blockIdx.x;
    int lane = threadIdx.x & 63, w = threadIdx.x >> 6;
    int s = gstart[gi], e = gstart[gi + 1];
    float gg = g[lane], bb = b[lane];
    float acc = 0.f;
    for (int n = s + w; n < e; n += 16) {
        float v = cur[(long)n * 64 + lane];
        float mu = wave_sum(v) * (1.f / 64.f);
        float d = v - mu;
        float var = wave_sum(d * d) * (1.f / 64.f);
        acc += fmaxf(d * rsqrtf(var + 1e-5f) * gg + bb, 0.f);
    }
    __shared__ float sh[16][64];
    sh[w][lane] = acc;
    __syncthreads();
    if (w == 0) {
        float tot = 0.f;
#pragma unroll
        for (int k = 0; k < 16; ++k) tot += sh[k][lane];
        out[gi * 64 + lane] = tot / fmaxf((float)(e - s), 1.f);
    }
}

extern "C" void kernel_launch(void* const* d_in, const int* in_sizes, int n_in,
                              void* d_out, int out_size, void* d_ws, size_t ws_size,
                              hipStream_t stream) {
    (void)in_sizes; (void)n_in; (void)out_size; (void)ws_size;
    const int* x         = (const int*)d_in[0];
    const int* edge_attr = (const int*)d_in[1];
    const int* src       = (const int*)d_in[2];
    const int* dst       = src + NE;
    const int* batch     = (const int*)d_in[3];
    const float* atom_emb = (const float*)d_in[4];
    const float* bond_emb = (const float*)d_in[5];
    const float* t        = (const float*)d_in[6];
    const float* W1       = (const float*)d_in[7];
    const float* b1       = (const float*)d_in[8];
    const float* g1       = (const float*)d_in[9];
    const float* bb1      = (const float*)d_in[10];
    const float* W2       = (const float*)d_in[11];
    const float* b2       = (const float*)d_in[12];
    const float* norm_g   = (const float*)d_in[13];
    const float* norm_b   = (const float*)d_in[14];
    float* out = (float*)d_out;

    size_t off = 0;
    auto alloc = [&](size_t bytes) {
        void* p = (char*)d_ws + off;
        off += (bytes + 255) & ~(size_t)255;
        return p;
    };
    int*    count  = (int*)alloc((size_t)NN * 4);
    int*    wofs   = (int*)alloc((size_t)NN * 4);
    int*    rowptr = (int*)alloc((size_t)(NN + 1) * 4);
    int*    bsum   = (int*)alloc(4096);
    int*    csr32  = (int*)alloc((size_t)NE * 4);
    __half* comb   = (__half*)alloc(1000 * 64 * 2);
    __half* xnH    = (__half*)alloc((size_t)NN * 64 * 2);
    __half* hhH    = (__half*)alloc((size_t)NN * 64 * 2);
    __half* oH     = (__half*)alloc((size_t)NN * 64 * 2);
    float*  cur    = (float*)alloc((size_t)NN * 64 * 4);
    int*    gstart = (int*)alloc((size_t)(NG + 1) * 4);
    __half* w1t    = (__half*)alloc((size_t)NL * 8192 * 2);
    __half* w2t    = (__half*)alloc((size_t)NL * 8192 * 2);

    hipMemsetAsync(count, 0, (size_t)NN * 4, stream);
    hipMemsetAsync(wofs, 0, (size_t)NN * 4, stream);

    const int EB = (NE + 255) / 256;
    const int SB = (NN + 255) / 256;
    const int WB = (NN * 64 + 255) / 256;

    k_count<<<EB, 256, 0, stream>>>(dst, count);
    k_scan1<<<SB, 256, 0, stream>>>(count, rowptr + 1, bsum, NN);
    k_scan2<<<1, 256, 0, stream>>>(bsum, SB);
    k_scan3<<<SB, 256, 0, stream>>>(rowptr, bsum, NN);
    k_fill<<<EB, 256, 0, stream>>>(src, dst, edge_attr, rowptr, wofs, csr32);
    k_comb<<<(1000 * 64 + 255) / 256, 256, 0, stream>>>(bond_emb, comb);
    k_atom<<<WB, 256, 0, stream>>>(x, atom_emb, xnH);
    k_bounds<<<SB, 256, 0, stream>>>(batch, gstart);
    k_packw<<<(NL * 8192 + 255) / 256, 256, 0, stream>>>(W1, W2, w1t, w2t);

    // Per layer: k_agg (hin -> oH), k_mlp (oH -> cur, hh). No buffer aliasing within a dispatch.
    const int AB = NN / 4;    // 20000 blocks
    const int MBK = NN / 64;  // 1250 blocks
    for (int l = 0; l < NL; ++l) {
        const __half* hin = (l == 0) ? xnH : hhH;
        __half* hh_out = (l < NL - 1) ? hhH : nullptr;
        const float* ngp = norm_g + (l + 1 < NL ? (l + 1) * 64 : 0);
        const float* nbp = norm_b + (l + 1 < NL ? (l + 1) * 64 : 0);
        k_agg<<<AB, 256, 0, stream>>>(hin, rowptr, csr32, comb, t, l, oH);
        k_mlp<<<MBK, 256, 0, stream>>>(oH, l, w1t, w2t, b1, g1, bb1, b2,
                                       cur, l > 0, hh_out, ngp, nbp);
    }
    k_pool2<<<NG, 1024, 0, stream>>>(cur, gstart, norm_g, norm_b, out);
}

// Round 14
// 528.952 us; speedup vs baseline: 2.9847x; 1.0234x over previous
//
#include <hip/hip_runtime.h>
#include <hip/hip_bf16.h>
#include <hip/hip_fp16.h>

#define NN 80000
#define NE 1280000
#define NL 4
#define NG 256

typedef __attribute__((ext_vector_type(8))) _Float16 half8;
typedef __attribute__((ext_vector_type(4))) float f32x4;

__device__ __forceinline__ float wave_sum(float v) {
    for (int off = 32; off; off >>= 1) v += __shfl_xor(v, off, 64);
    return v;
}

// ---------------- CSR build ----------------
__global__ void k_count(const int* __restrict__ idx, int* __restrict__ cnt) {
    int e = blockIdx.x * 256 + threadIdx.x;
    if (e < NE) atomicAdd(&cnt[idx[e]], 1);
}

__global__ void k_scan1(const int* __restrict__ in, int* __restrict__ out,
                        int* __restrict__ bsum, int n) {
    __shared__ int ws[4];
    int i = blockIdx.x * 256 + threadIdx.x;
    int v = (i < n) ? in[i] : 0;
    int lane = threadIdx.x & 63, w = threadIdx.x >> 6;
    for (int off = 1; off < 64; off <<= 1) {
        int t = __shfl_up(v, off, 64);
        if (lane >= off) v += t;
    }
    if (lane == 63) ws[w] = v;
    __syncthreads();
    if (threadIdx.x == 0) {
        int acc = 0;
        for (int k = 0; k < 4; k++) { int t = ws[k]; ws[k] = acc; acc += t; }
    }
    __syncthreads();
    v += ws[w];
    if (i < n) out[i] = v;
    if (threadIdx.x == 255) bsum[blockIdx.x] = v;
}

__global__ void k_scan2(int* __restrict__ bsum, int nb) {
    __shared__ int ws[4];
    __shared__ int carry;
    if (threadIdx.x == 0) carry = 0;
    __syncthreads();
    for (int base = 0; base < nb; base += 256) {
        int i = base + threadIdx.x;
        int v = (i < nb) ? bsum[i] : 0;
        int lane = threadIdx.x & 63, w = threadIdx.x >> 6;
        for (int off = 1; off < 64; off <<= 1) {
            int t = __shfl_up(v, off, 64);
            if (lane >= off) v += t;
        }
        if (lane == 63) ws[w] = v;
        __syncthreads();
        if (threadIdx.x == 0) {
            int acc = carry;
            for (int k = 0; k < 4; k++) { int t = ws[k]; ws[k] = acc; acc += t; }
            carry = acc;
        }
        __syncthreads();
        v += ws[w];
        if (i < nb) bsum[i] = v;
        __syncthreads();
    }
}

__global__ void k_scan3(int* __restrict__ rowptr, const int* __restrict__ bsum, int n) {
    int i = blockIdx.x * 256 + threadIdx.x;
    if (i < n) {
        int off = (blockIdx.x > 0) ? bsum[blockIdx.x - 1] : 0;
        rowptr[1 + i] += off;
    }
    if (i == 0 && blockIdx.x == 0) rowptr[0] = 0;
}

__global__ void k_fill(const int* __restrict__ src, const int* __restrict__ dst,
                       const int* __restrict__ eattr, const int* __restrict__ rowptr,
                       int* __restrict__ wofs, int* __restrict__ csr32) {
    int e = blockIdx.x * 256 + threadIdx.x;
    if (e >= NE) return;
    int d = dst[e];
    int pos = rowptr[d] + atomicAdd(&wofs[d], 1);
    int a0 = eattr[e * 3], a1 = eattr[e * 3 + 1], a2 = eattr[e * 3 + 2];
    csr32[pos] = (src[e] << 10) | (a0 + a1 * 10 + a2 * 100);
}

// ---------------- encoders / weight packing ----------------
__global__ void k_comb(const float* __restrict__ bond_emb, __half* __restrict__ comb) {
    int wid = (blockIdx.x * 256 + threadIdx.x) >> 6;
    int lane = threadIdx.x & 63;
    if (wid >= 1000) return;
    int a0 = wid % 10, a1 = (wid / 10) % 10, a2 = wid / 100;
    comb[wid * 64 + lane] = __float2half(bond_emb[a0 * 64 + lane] +
                                         bond_emb[(10 + a1) * 64 + lane] +
                                         bond_emb[(20 + a2) * 64 + lane]);
}

__global__ void k_atom(const int* __restrict__ x, const float* __restrict__ atom_emb,
                       __half* __restrict__ xn) {
    int wid = (blockIdx.x * 256 + threadIdx.x) >> 6;
    int lane = threadIdx.x & 63;
    if (wid >= NN) return;
    float acc = 0.f;
#pragma unroll
    for (int f = 0; f < 9; f++) {
        int idx = x[wid * 9 + f] + f * 100;
        acc += atom_emb[idx * 64 + lane];
    }
    xn[wid * 64 + lane] = __float2half(acc);
}

// w1t[l][n(128)][k(64)] = W1[l][k][n] ;  w2t[l][n(64)][k(128)] = W2[l][k][n]  (fp16, B^T layout)
__global__ void k_packw(const float* __restrict__ W1, const float* __restrict__ W2,
                        __half* __restrict__ w1t, __half* __restrict__ w2t) {
    int i = blockIdx.x * 256 + threadIdx.x;
    if (i >= NL * 8192) return;
    int l = i >> 13, r = i & 8191;
    int n1 = r >> 6, k1 = r & 63;
    w1t[i] = __float2half(W1[(l * 64 + k1) * 128 + n1]);
    int n2 = r >> 7, k2 = r & 127;
    w2t[i] = __float2half(W2[(l * 128 + k2) * 64 + n2]);
}

// ---------------- aggregation: 2 nodes per wave, dual streams, 16 loads in flight ----------
__global__ __launch_bounds__(256) void k_agg(
    const __half* __restrict__ hin, const int* __restrict__ rowptr,
    const int* __restrict__ csr32, const __half* __restrict__ comb,
    const float* __restrict__ t, int l, __half* __restrict__ o) {
    int w = blockIdx.x * 4 + (threadIdx.x >> 6);   // NN/2 == 10000*4 waves
    int lane = threadIdx.x & 63;
    int n0 = w * 2;
    float tl = t[l];
    long oi0 = (long)n0 * 64 + lane;
    long oi1 = oi0 + 64;
    float hr0 = __half2float(hin[oi0]);
    float hr1 = __half2float(hin[oi1]);
    int rs0 = rowptr[n0], mid = rowptr[n0 + 1], re1 = rowptr[n0 + 2];
    int c0 = mid - rs0, c1 = re1 - mid;
    int cmin = min(c0, c1);

    float dA0 = 0.f, nA0 = 0.f, dA1 = 0.f, nA1 = 0.f;   // node0 dual acc
    float dB0 = 0.f, nB0 = 0.f, dB1 = 0.f, nB1 = 0.f;   // node1 dual acc
    int i = 0, i4 = cmin & ~3;
    for (; i < i4; i += 4) {
        int a0 = csr32[rs0 + i],     a1 = csr32[rs0 + i + 1];
        int a2 = csr32[rs0 + i + 2], a3 = csr32[rs0 + i + 3];
        int b0 = csr32[mid + i],     b1 = csr32[mid + i + 1];
        int b2 = csr32[mid + i + 2], b3 = csr32[mid + i + 3];
        float ha0 = __half2float(hin[(long)(a0 >> 10) * 64 + lane]);
        float ca0 = __half2float(comb[(a0 & 1023) * 64 + lane]);
        float ha1 = __half2float(hin[(long)(a1 >> 10) * 64 + lane]);
        float ca1 = __half2float(comb[(a1 & 1023) * 64 + lane]);
        float ha2 = __half2float(hin[(long)(a2 >> 10) * 64 + lane]);
        float ca2 = __half2float(comb[(a2 & 1023) * 64 + lane]);
        float ha3 = __half2float(hin[(long)(a3 >> 10) * 64 + lane]);
        float ca3 = __half2float(comb[(a3 & 1023) * 64 + lane]);
        float hb0 = __half2float(hin[(long)(b0 >> 10) * 64 + lane]);
        float cb0 = __half2float(comb[(b0 & 1023) * 64 + lane]);
        float hb1 = __half2float(hin[(long)(b1 >> 10) * 64 + lane]);
        float cb1 = __half2float(comb[(b1 & 1023) * 64 + lane]);
        float hb2 = __half2float(hin[(long)(b2 >> 10) * 64 + lane]);
        float cb2 = __half2float(comb[(b2 & 1023) * 64 + lane]);
        float hb3 = __half2float(hin[(long)(b3 >> 10) * 64 + lane]);
        float cb3 = __half2float(comb[(b3 & 1023) * 64 + lane]);
        float ma0 = fmaxf(ha0 + ca0, 0.f) + 1e-7f;
        float ma1 = fmaxf(ha1 + ca1, 0.f) + 1e-7f;
        float ma2 = fmaxf(ha2 + ca2, 0.f) + 1e-7f;
        float ma3 = fmaxf(ha3 + ca3, 0.f) + 1e-7f;
        float mb0 = fmaxf(hb0 + cb0, 0.f) + 1e-7f;
        float mb1 = fmaxf(hb1 + cb1, 0.f) + 1e-7f;
        float mb2 = fmaxf(hb2 + cb2, 0.f) + 1e-7f;
        float mb3 = fmaxf(hb3 + cb3, 0.f) + 1e-7f;
        float ea0 = __expf(ma0 * tl), ea1 = __expf(ma1 * tl);
        float ea2 = __expf(ma2 * tl), ea3 = __expf(ma3 * tl);
        float eb0 = __expf(mb0 * tl), eb1 = __expf(mb1 * tl);
        float eb2 = __expf(mb2 * tl), eb3 = __expf(mb3 * tl);
        dA0 += ea0; nA0 = fmaf(ea0, ma0, nA0);
        dA1 += ea1; nA1 = fmaf(ea1, ma1, nA1);
        dA0 += ea2; nA0 = fmaf(ea2, ma2, nA0);
        dA1 += ea3; nA1 = fmaf(ea3, ma3, nA1);
        dB0 += eb0; nB0 = fmaf(eb0, mb0, nB0);
        dB1 += eb1; nB1 = fmaf(eb1, mb1, nB1);
        dB0 += eb2; nB0 = fmaf(eb2, mb2, nB0);
        dB1 += eb3; nB1 = fmaf(eb3, mb3, nB1);
    }
    for (; i < cmin; ++i) {
        int a = csr32[rs0 + i], b = csr32[mid + i];
        float ha = __half2float(hin[(long)(a >> 10) * 64 + lane]);
        float ca = __half2float(comb[(a & 1023) * 64 + lane]);
        float hb = __half2float(hin[(long)(b >> 10) * 64 + lane]);
        float cb = __half2float(comb[(b & 1023) * 64 + lane]);
        float ma = fmaxf(ha + ca, 0.f) + 1e-7f;
        float mb = fmaxf(hb + cb, 0.f) + 1e-7f;
        float ea = __expf(ma * tl), eb = __expf(mb * tl);
        dA0 += ea; nA0 = fmaf(ea, ma, nA0);
        dB0 += eb; nB0 = fmaf(eb, mb, nB0);
    }
    for (int p = rs0 + cmin; p < mid; ++p) {          // node0 remainder (uniform branch)
        int a = csr32[p];
        float ha = __half2float(hin[(long)(a >> 10) * 64 + lane]);
        float ca = __half2float(comb[(a & 1023) * 64 + lane]);
        float ma = fmaxf(ha + ca, 0.f) + 1e-7f;
        float ea = __expf(ma * tl);
        dA0 += ea; nA0 = fmaf(ea, ma, nA0);
    }
    for (int p = mid + cmin; p < re1; ++p) {          // node1 remainder
        int b = csr32[p];
        float hb = __half2float(hin[(long)(b >> 10) * 64 + lane]);
        float cb = __half2float(comb[(b & 1023) * 64 + lane]);
        float mb = fmaxf(hb + cb, 0.f) + 1e-7f;
        float eb = __expf(mb * tl);
        dB0 += eb; nB0 = fmaf(eb, mb, nB0);
    }
    float dA = dA0 + dA1, nA = nA0 + nA1;
    float dB = dB0 + dB1, nB = nB0 + nB1;
    o[oi0] = __float2half(nA / (dA + 1e-16f) + hr0);
    o[oi1] = __float2half(nB / (dB + 1e-16f) + hr1);
}

// ---------------- MFMA MLP: 16 nodes/wave, 4 waves/block ----------------
__global__ __launch_bounds__(256) void k_mlp(
    const __half* __restrict__ o, int l,
    const __half* __restrict__ w1t, const __half* __restrict__ w2t,
    const float* __restrict__ b1, const float* __restrict__ g1,
    const float* __restrict__ bb1, const float* __restrict__ b2,
    float* __restrict__ cur, int residual,
    __half* __restrict__ hh, const float* __restrict__ ng, const float* __restrict__ nbv) {
    __shared__ __half midL[4][16][136];
    int w = threadIdx.x >> 6, lane = threadIdx.x & 63;
    int node0 = blockIdx.x * 64 + w * 16;           // NN == 1250*64
    int lm = lane & 15, lh = lane >> 4;

    const __half* ob = o + (long)(node0 + lm) * 64 + lh * 8;
    half8 a0 = *(const half8*)(ob);
    half8 a1 = *(const half8*)(ob + 32);
    const __half* w1b = w1t + l * 8192 + lm * 64 + lh * 8;
    f32x4 acc[8];
#pragma unroll
    for (int nb = 0; nb < 8; ++nb) {
        f32x4 c = {0.f, 0.f, 0.f, 0.f};
        half8 b0 = *(const half8*)(w1b + nb * 1024);
        half8 bx = *(const half8*)(w1b + nb * 1024 + 32);
        c = __builtin_amdgcn_mfma_f32_16x16x32_f16(a0, b0, c, 0, 0, 0);
        c = __builtin_amdgcn_mfma_f32_16x16x32_f16(a1, bx, c, 0, 0, 0);
        acc[nb] = c;
    }

    float bv[8], gv[8], bbv[8];
#pragma unroll
    for (int nb = 0; nb < 8; ++nb) {
        int n = l * 128 + nb * 16 + lm;
        bv[nb] = b1[n]; gv[nb] = g1[n]; bbv[nb] = bb1[n];
    }
    float ps[4] = {0.f, 0.f, 0.f, 0.f};
#pragma unroll
    for (int nb = 0; nb < 8; ++nb)
#pragma unroll
        for (int r = 0; r < 4; ++r) { acc[nb][r] += bv[nb]; ps[r] += acc[nb][r]; }
#pragma unroll
    for (int r = 0; r < 4; ++r) {
        for (int off = 1; off < 16; off <<= 1) ps[r] += __shfl_xor(ps[r], off, 64);
        ps[r] *= (1.f / 128.f);
    }
    float pv[4] = {0.f, 0.f, 0.f, 0.f};
#pragma unroll
    for (int nb = 0; nb < 8; ++nb)
#pragma unroll
        for (int r = 0; r < 4; ++r) { float d = acc[nb][r] - ps[r]; pv[r] = fmaf(d, d, pv[r]); }
#pragma unroll
    for (int r = 0; r < 4; ++r) {
        for (int off = 1; off < 16; off <<= 1) pv[r] += __shfl_xor(pv[r], off, 64);
        pv[r] = rsqrtf(pv[r] * (1.f / 128.f) + 1e-5f);
    }
#pragma unroll
    for (int nb = 0; nb < 8; ++nb)
#pragma unroll
        for (int r = 0; r < 4; ++r) {
            float m = fmaxf((acc[nb][r] - ps[r]) * pv[r] * gv[nb] + bbv[nb], 0.f);
            midL[w][lh * 4 + r][nb * 16 + lm] = __float2half(m);
        }

    const __half* mrow = &midL[w][lm][lh * 8];
    const __half* w2b = w2t + l * 8192 + lm * 128 + lh * 8;
    f32x4 acc2[4];
#pragma unroll
    for (int nb = 0; nb < 4; ++nb) acc2[nb] = (f32x4){0.f, 0.f, 0.f, 0.f};
#pragma unroll
    for (int kb = 0; kb < 4; ++kb) {
        half8 a = *(const half8*)(mrow + kb * 32);
#pragma unroll
        for (int nb = 0; nb < 4; ++nb) {
            half8 b = *(const half8*)(w2b + nb * 2048 + kb * 32);
            acc2[nb] = __builtin_amdgcn_mfma_f32_16x16x32_f16(a, b, acc2[nb], 0, 0, 0);
        }
    }

    float b2v[4], cps[4] = {0.f, 0.f, 0.f, 0.f};
    float cv[4][4];
#pragma unroll
    for (int nb = 0; nb < 4; ++nb) b2v[nb] = b2[l * 64 + nb * 16 + lm];
#pragma unroll
    for (int nb = 0; nb < 4; ++nb)
#pragma unroll
        for (int r = 0; r < 4; ++r) {
            long ci = (long)(node0 + lh * 4 + r) * 64 + nb * 16 + lm;
            float z = acc2[nb][r] + b2v[nb] + (residual ? cur[ci] : 0.f);
            cur[ci] = z;
            cv[nb][r] = z;
            cps[r] += z;
        }
    if (hh) {
        float gn[4], bn[4], mu[4], rv[4];
        float pvv[4] = {0.f, 0.f, 0.f, 0.f};
#pragma unroll
        for (int nb = 0; nb < 4; ++nb) { gn[nb] = ng[nb * 16 + lm]; bn[nb] = nbv[nb * 16 + lm]; }
#pragma unroll
        for (int r = 0; r < 4; ++r) {
            float s = cps[r];
            for (int off = 1; off < 16; off <<= 1) s += __shfl_xor(s, off, 64);
            mu[r] = s * (1.f / 64.f);
        }
#pragma unroll
        for (int nb = 0; nb < 4; ++nb)
#pragma unroll
            for (int r = 0; r < 4; ++r) { float d = cv[nb][r] - mu[r]; pvv[r] = fmaf(d, d, pvv[r]); }
#pragma unroll
        for (int r = 0; r < 4; ++r) {
            float s = pvv[r];
            for (int off = 1; off < 16; off <<= 1) s += __shfl_xor(s, off, 64);
            rv[r] = rsqrtf(s * (1.f / 64.f) + 1e-5f);
        }
#pragma unroll
        for (int nb = 0; nb < 4; ++nb)
#pragma unroll
            for (int r = 0; r < 4; ++r) {
                long ci = (long)(node0 + lh * 4 + r) * 64 + nb * 16 + lm;
                hh[ci] = __float2half(fmaxf((cv[nb][r] - mu[r]) * rv[r] * gn[nb] + bn[nb], 0.f));
            }
    }
}

// ---------------- pooling (atomic-free, batch sorted) ----------------
__global__ void k_bounds(const int* __restrict__ batch, int* __restrict__ gstart) {
    int i = blockIdx.x * 256 + threadIdx.x;
    if (i >= NN) return;
    int b = batch[i];
    if (i == 0) {
        for (int g = 0; g <= b; ++g) gstart[g] = 0;
    } else {
        int pb = batch[i - 1];
        for (int g = pb + 1; g <= b; ++g) gstart[g] = i;
    }
    if (i == NN - 1) {
        for (int g = b + 1; g <= NG; ++g) gstart[g] = NN;
    }
}

__global__ __launch_bounds__(1024) void k_pool2(
    const float* __restrict__ cur, const int* __restrict__ gstart,
    const float* __restrict__ g, const float* __restrict__ b,
    float* __restrict__ out) {
    int gi = blockIdx.x;
    int lane = threadIdx.x & 63, w = threadIdx.x >> 6;
    int s = gstart[gi], e = gstart[gi + 1];
    float gg = g[lane], bb = b[lane];
    float acc = 0.f;
    for (int n = s + w; n < e; n += 16) {
        float v = cur[(long)n * 64 + lane];
        float mu = wave_sum(v) * (1.f / 64.f);
        float d = v - mu;
        float var = wave_sum(d * d) * (1.f / 64.f);
        acc += fmaxf(d * rsqrtf(var + 1e-5f) * gg + bb, 0.f);
    }
    __shared__ float sh[16][64];
    sh[w][lane] = acc;
    __syncthreads();
    if (w == 0) {
        float tot = 0.f;
#pragma unroll
        for (int k = 0; k < 16; ++k) tot += sh[k][lane];
        out[gi * 64 + lane] = tot / fmaxf((float)(e - s), 1.f);
    }
}

extern "C" void kernel_launch(void* const* d_in, const int* in_sizes, int n_in,
                              void* d_out, int out_size, void* d_ws, size_t ws_size,
                              hipStream_t stream) {
    (void)in_sizes; (void)n_in; (void)out_size; (void)ws_size;
    const int* x         = (const int*)d_in[0];
    const int* edge_attr = (const int*)d_in[1];
    const int* src       = (const int*)d_in[2];
    const int* dst       = src + NE;
    const int* batch     = (const int*)d_in[3];
    const float* atom_emb = (const float*)d_in[4];
    const float* bond_emb = (const float*)d_in[5];
    const float* t        = (const float*)d_in[6];
    const float* W1       = (const float*)d_in[7];
    const float* b1       = (const float*)d_in[8];
    const float* g1       = (const float*)d_in[9];
    const float* bb1      = (const float*)d_in[10];
    const float* W2       = (const float*)d_in[11];
    const float* b2       = (const float*)d_in[12];
    const float* norm_g   = (const float*)d_in[13];
    const float* norm_b   = (const float*)d_in[14];
    float* out = (float*)d_out;

    size_t off = 0;
    auto alloc = [&](size_t bytes) {
        void* p = (char*)d_ws + off;
        off += (bytes + 255) & ~(size_t)255;
        return p;
    };
    int*    count  = (int*)alloc((size_t)NN * 4);
    int*    wofs   = (int*)alloc((size_t)NN * 4);
    int*    rowptr = (int*)alloc((size_t)(NN + 1) * 4);
    int*    bsum   = (int*)alloc(4096);
    int*    csr32  = (int*)alloc((size_t)NE * 4);
    __half* comb   = (__half*)alloc(1000 * 64 * 2);
    __half* xnH    = (__half*)alloc((size_t)NN * 64 * 2);
    __half* hhH    = (__half*)alloc((size_t)NN * 64 * 2);
    __half* oH     = (__half*)alloc((size_t)NN * 64 * 2);
    float*  cur    = (float*)alloc((size_t)NN * 64 * 4);
    int*    gstart = (int*)alloc((size_t)(NG + 1) * 4);
    __half* w1t    = (__half*)alloc((size_t)NL * 8192 * 2);
    __half* w2t    = (__half*)alloc((size_t)NL * 8192 * 2);

    hipMemsetAsync(count, 0, (size_t)NN * 4, stream);
    hipMemsetAsync(wofs, 0, (size_t)NN * 4, stream);

    const int EB = (NE + 255) / 256;
    const int SB = (NN + 255) / 256;
    const int WB = (NN * 64 + 255) / 256;

    k_count<<<EB, 256, 0, stream>>>(dst, count);
    k_scan1<<<SB, 256, 0, stream>>>(count, rowptr + 1, bsum, NN);
    k_scan2<<<1, 256, 0, stream>>>(bsum, SB);
    k_scan3<<<SB, 256, 0, stream>>>(rowptr, bsum, NN);
    k_fill<<<EB, 256, 0, stream>>>(src, dst, edge_attr, rowptr, wofs, csr32);
    k_comb<<<(1000 * 64 + 255) / 256, 256, 0, stream>>>(bond_emb, comb);
    k_atom<<<WB, 256, 0, stream>>>(x, atom_emb, xnH);
    k_bounds<<<SB, 256, 0, stream>>>(batch, gstart);
    k_packw<<<(NL * 8192 + 255) / 256, 256, 0, stream>>>(W1, W2, w1t, w2t);

    const int AB = NN / 8;    // 10000 blocks (2 nodes/wave, 4 waves/block)
    const int MBK = NN / 64;  // 1250 blocks
    for (int l = 0; l < NL; ++l) {
        const __half* hin = (l == 0) ? xnH : hhH;
        __half* hh_out = (l < NL - 1) ? hhH : nullptr;
        const float* ngp = norm_g + (l + 1 < NL ? (l + 1) * 64 : 0);
        const float* nbp = norm_b + (l + 1 < NL ? (l + 1) * 64 : 0);
        k_agg<<<AB, 256, 0, stream>>>(hin, rowptr, csr32, comb, t, l, oH);
        k_mlp<<<MBK, 256, 0, stream>>>(oH, l, w1t, w2t, b1, g1, bb1, b2,
                                       cur, l > 0, hh_out, ngp, nbp);
    }
    k_pool2<<<NG, 1024, 0, stream>>>(cur, gstart, norm_g, norm_b, out);
}